// Round 8
// baseline (346.421 us; speedup 1.0000x reference)
//
#include <hip/hip_runtime.h>
#include <hip/hip_fp16.h>
#include <math.h>

#define H 256
#define COLSN 64
#define ROWSN 200000
#define T_STEPS 4
#define QLEN 40
#define NNUM 5
#define NOPS 9

// workspace float offsets
#define WS_XWB    0          // 40*256
#define WS_Q      10240      // 256
#define WS_AOP    10496      // 4*16
#define WS_ACOL   10560      // 4*64
#define WS_PIV    10816      // [0]=g_pivot [1]=l_pivot
#define WS_TICKET 10818
#define WS_PACC8  10824      // 8 accumulators: dot[4], cnt[4]
#define WS_MOP    11104      // 9*256
#define WS_MCOL   13408      // 64*256

#define NTBL_TILES  1563     // tiles of 128 rows: 1563*128 = 200064 >= 200000
#define NTBL_BLOCKS 782      // grid-stride: each block does 2 tiles (one does 1)

// DPP-based partial-sum add (VALU pipe)
template<int CTRL>
__device__ __forceinline__ float dpp_add(float x) {
    int xi = __float_as_int(x);
    int yi = __builtin_amdgcn_update_dpp(0, xi, CTRL, 0xF, 0xF, true);
    return x + __int_as_float(yi);
}
#define DPP_XOR1 0xB1   // quad_perm [1,0,3,2]
#define DPP_XOR2 0x4E   // quad_perm [2,3,0,1]
#define DPP_HMIR 0x141  // row_half_mirror
#define DPP_MIR  0x140  // row_mirror

__device__ __forceinline__ float reduce16(float v) {
    v = dpp_add<DPP_XOR1>(v);
    v = dpp_add<DPP_XOR2>(v);
    v = dpp_add<DPP_HMIR>(v);
    v = dpp_add<DPP_MIR>(v);
    return v;
}

__device__ __forceinline__ float fast_tanh(float x) {
    float cx = fminf(15.f, fmaxf(-15.f, x));
    float e = __expf(2.f * cx);
    return __fdividef(e - 1.f, e + 1.f);
}

__device__ __forceinline__ float dot4(float4 a, float4 b) {
    return a.x * b.x + a.y * b.y + a.z * b.z + a.w * b.w;
}

// LDS swizzle: +4 floats pad per 16
__device__ __forceinline__ int sw(int i) { return i + ((i >> 4) << 2); }

// ==== k_pre: blocks 0..39 -> X@Wx+b ; blocks 40..47 -> M matrices ====
__global__ __launch_bounds__(256) void k_pre(const int* __restrict__ iq,
        const float* __restrict__ E, const float* __restrict__ Wx,
        const float* __restrict__ b, const float* __restrict__ W_hc,
        const float* __restrict__ op_emb, const float* __restrict__ col_emb,
        float* __restrict__ ws) {
    int blk = blockIdx.x;
    int tid = threadIdx.x;
    if (blk < QLEN) {
        if (blk == 0 && tid < 16) ws[WS_TICKET + tid] = 0.f;  // ticket + PACC8
        int word = iq[blk];
        const float* erow = E + (long)word * H;
        float acc = b[tid];
        #pragma unroll 8
        for (int j = 0; j < H; ++j) acc += erow[j] * Wx[j * H + tid];
        ws[WS_XWB + blk * H + tid] = acc;
    } else {
        __shared__ __attribute__((aligned(16))) float tile[32][516];
        int bi = blk - QLEN;
        int ibase = bi * 32;
        const float4* src = (const float4*)(W_hc + (long)ibase * 2 * H);
        for (int idx = tid; idx < 32 * 128; idx += 256) {
            int row = idx >> 7, c4 = idx & 127;
            *(float4*)&tile[row][c4 * 4] = src[idx];
        }
        __syncthreads();
        int l8 = tid & 7;
        int io = tid >> 3;
        for (int k = 0; k < NOPS + COLSN; ++k) {
            const float* emb = (k < NOPS) ? (op_emb + k * H) : (col_emb + (k - NOPS) * H);
            int coff = (k < NOPS) ? 0 : H;
            float s = 0.f;
            const float* ep = emb + l8 * 32;
            const float* tr = &tile[io][coff + l8 * 32];
            #pragma unroll
            for (int ss = 0; ss < 8; ++ss) {
                int q4 = (ss + io) & 7;
                float4 e4 = *(const float4*)&ep[q4 * 4];
                float4 t4 = *(const float4*)&tr[q4 * 4];
                s += dot4(e4, t4);
            }
            s += __shfl_xor(s, 1);
            s += __shfl_xor(s, 2);
            s += __shfl_xor(s, 4);
            if (l8 == 0) {
                int dst = (k < NOPS) ? (WS_MOP + k * H) : (WS_MCOL + (k - NOPS) * H);
                ws[dst + ibase + io] = s;
            }
        }
    }
}

// ==== k_rnn: round-2 replica (measured ~42 us). 1024 thr, R=2 x P=8. ====
__global__ __launch_bounds__(1024) void k_rnn(const float* __restrict__ Wh,
                      const int* __restrict__ lwi,
                      const float* __restrict__ U, const float* __restrict__ qn,
                      float* __restrict__ ws) {
    __shared__ __attribute__((aligned(16))) float hbuf[2][288];
    __shared__ __attribute__((aligned(16))) float xwb[QLEN][H];
    __shared__ float Z[NNUM][H];
    __shared__ float lg[10];
    int tid = threadIdx.x;
    int g = tid >> 3;            // output pair 0..127
    int p = tid & 7;             // j-slice 0..7 (32 j each)

    float2 w2[32];
    #pragma unroll
    for (int jj = 0; jj < 32; ++jj)
        w2[jj] = *(const float2*)&Wh[(p * 32 + jj) * H + g * 2];

    {
        const float4* src = (const float4*)&ws[WS_XWB];
        float4* dst = (float4*)&xwb[0][0];
        for (int idx = tid; idx < QLEN * H / 4; idx += 1024) dst[idx] = src[idx];
    }
    if (tid < H) hbuf[0][tid + ((tid >> 5) << 2)] = 0.f;  // swz: i + 4*(i>>5)
    __syncthreads();

    int lw0 = lwi[0], lw1 = lwi[1], lw2 = lwi[2], lw3 = lwi[3], lw4 = lwi[4];
    int cur = 0;
    for (int t = 0; t < QLEN; ++t) {
        const float4* hv = (const float4*)&hbuf[cur][p * 36];  // swz(p*32)=p*36
        float a0 = 0.f, a1 = 0.f;
        #pragma unroll
        for (int q4 = 0; q4 < 8; ++q4) {
            float4 h4 = hv[q4];
            float2 wa = w2[q4 * 4 + 0];
            float2 wb = w2[q4 * 4 + 1];
            float2 wc = w2[q4 * 4 + 2];
            float2 wd = w2[q4 * 4 + 3];
            a0 += h4.x * wa.x; a1 += h4.x * wa.y;
            a0 += h4.y * wb.x; a1 += h4.y * wb.y;
            a0 += h4.z * wc.x; a1 += h4.z * wc.y;
            a0 += h4.w * wd.x; a1 += h4.w * wd.y;
        }
        a0 = dpp_add<DPP_XOR1>(a0); a0 = dpp_add<DPP_XOR2>(a0); a0 = dpp_add<DPP_HMIR>(a0);
        a1 = dpp_add<DPP_XOR1>(a1); a1 = dpp_add<DPP_XOR2>(a1); a1 = dpp_add<DPP_HMIR>(a1);
        if (p < 2) {
            float s = (p == 0) ? a0 : a1;
            int i = g * 2 + p;
            float hn = fast_tanh(xwb[t][i] + s);
            hbuf[cur ^ 1][i + ((i >> 5) << 2)] = hn;
            if (t == lw0) Z[0][i] = hn;
            if (t == lw1) Z[1][i] = hn;
            if (t == lw2) Z[2][i] = hn;
            if (t == lw3) Z[3][i] = hn;
            if (t == lw4) Z[4][i] = hn;
        }
        __syncthreads();
        cur ^= 1;
    }
    if (tid < H) ws[WS_Q + tid] = hbuf[cur][tid + ((tid >> 5) << 2)];

    int grp = tid >> 5;
    int lane = tid & 31;
    if (grp < 10) {
        int u = grp / 5, n = grp % 5;
        float s = 0.f;
        #pragma unroll
        for (int k = 0; k < 8; ++k) {
            int j = lane + k * 32;
            s += Z[n][j] * U[u * H + j];
        }
        s += __shfl_xor(s, 1);
        s += __shfl_xor(s, 2);
        s += __shfl_xor(s, 4);
        s += __shfl_xor(s, 8);
        s += __shfl_xor(s, 16);
        if (lane == 0) lg[grp] = s;
    }
    __syncthreads();
    if (tid < 2) {
        float m = -1e30f;
        for (int n = 0; n < 5; ++n) m = fmaxf(m, lg[tid * 5 + n]);
        float e[5], s = 0.f;
        for (int n = 0; n < 5; ++n) { e[n] = expf(lg[tid * 5 + n] - m); s += e[n]; }
        float piv = 0.f;
        for (int n = 0; n < 5; ++n) piv += (e[n] / s) * qn[n];
        ws[WS_PIV + (tid == 0 ? 1 : 0)] = piv;   // PIV[0]=g, PIV[1]=l
    }
}

// ==== k_sel: selector, 512 threads (2 waves/SIMD -> 256 VGPR cap). ====
// fp16 weight cache wpk[192]: EVERY loop touching wpk is FULLY unrolled so
// all indices are compile-time constants (else the array goes to scratch).
__global__ __launch_bounds__(512)
__attribute__((amdgpu_waves_per_eu(2, 2)))
void k_sel(const float* __restrict__ W_op, const float* __restrict__ W_col,
           const float* __restrict__ W_hh, const float* __restrict__ op_emb,
           const float* __restrict__ col_emb, float* __restrict__ ws) {
    __shared__ __attribute__((aligned(16))) float qsw[320];
    __shared__ __attribute__((aligned(16))) float hhsw[320];
    __shared__ __attribute__((aligned(16))) float uopsw[320];
    __shared__ __attribute__((aligned(16))) float ucolsw[320];
    __shared__ float Pop[H], Pcol[H], vhh[H];
    __shared__ float lgs[80];
    __shared__ float aop_s[16], acol_s[64];

    const int tid = threadIdx.x;     // 512
    const int og = tid >> 4;         // 0..31
    const int p  = tid & 15;         // 0..15
    const int pb = p * 20;

    if (tid < H) qsw[sw(tid)] = ws[WS_Q + tid];
    if (tid < 320) hhsw[tid] = 0.f;
    __syncthreads();

    // ---- fp16 weight cache: 24 rows x 16 cols per thread (full unroll!) ----
    __half2 wpk[192];
    #pragma unroll
    for (int m = 0; m < 24; ++m) {
        int o = m * 32 + og;         // 0..767
        const float* row;
        if (m < 8)       row = &W_op[(long)o * 2 * H + H];
        else if (m < 16) row = &W_col[(long)(o - H) * 2 * H + H];
        else             row = &W_hh[(long)(o - 2 * H) * H];
        row += p * 16;
        float4 r0 = *(const float4*)&row[0];
        float4 r1 = *(const float4*)&row[4];
        float4 r2 = *(const float4*)&row[8];
        float4 r3 = *(const float4*)&row[12];
        wpk[m * 8 + 0] = __floats2half2_rn(r0.x, r0.y);
        wpk[m * 8 + 1] = __floats2half2_rn(r0.z, r0.w);
        wpk[m * 8 + 2] = __floats2half2_rn(r1.x, r1.y);
        wpk[m * 8 + 3] = __floats2half2_rn(r1.z, r1.w);
        wpk[m * 8 + 4] = __floats2half2_rn(r2.x, r2.y);
        wpk[m * 8 + 5] = __floats2half2_rn(r2.z, r2.w);
        wpk[m * 8 + 6] = __floats2half2_rn(r3.x, r3.y);
        wpk[m * 8 + 7] = __floats2half2_rn(r3.z, r3.w);
    }

    // ---- prologue: P = W[:, :256] @ q (streamed once, fp32) ----
    {
        float4 q0 = *(const float4*)&qsw[pb + 0];
        float4 q1 = *(const float4*)&qsw[pb + 4];
        float4 q2 = *(const float4*)&qsw[pb + 8];
        float4 q3 = *(const float4*)&qsw[pb + 12];
        #pragma unroll 4
        for (int mm = 0; mm < 16; ++mm) {
            int o = mm * 32 + og;    // 0..511
            const float* row = (o < H) ? &W_op[(long)o * 2 * H]
                                       : &W_col[(long)(o - H) * 2 * H];
            row += p * 16;
            float4 r0 = *(const float4*)&row[0];
            float4 r1 = *(const float4*)&row[4];
            float4 r2 = *(const float4*)&row[8];
            float4 r3 = *(const float4*)&row[12];
            float s = dot4(r0, q0) + dot4(r1, q1) + dot4(r2, q2) + dot4(r3, q3);
            s = reduce16(s);
            if (p == 0) { if (o < H) Pop[o] = s; else Pcol[o - H] = s; }
        }
    }
    __syncthreads();

    for (int t = 0; t < T_STEPS; ++t) {
        // stage A: u_op, u_col, vhh from register-resident fp16 weights
        {
            float4 h0 = *(const float4*)&hhsw[pb + 0];
            float4 h1 = *(const float4*)&hhsw[pb + 4];
            float4 h2 = *(const float4*)&hhsw[pb + 8];
            float4 h3 = *(const float4*)&hhsw[pb + 12];
            float hv[16] = {h0.x,h0.y,h0.z,h0.w, h1.x,h1.y,h1.z,h1.w,
                            h2.x,h2.y,h2.z,h2.w, h3.x,h3.y,h3.z,h3.w};
            #pragma unroll
            for (int m = 0; m < 24; ++m) {
                float s = 0.f;
                #pragma unroll
                for (int jj = 0; jj < 8; ++jj) {
                    float2 w = __half22float2(wpk[m * 8 + jj]);
                    s += w.x * hv[2 * jj] + w.y * hv[2 * jj + 1];
                }
                s = reduce16(s);
                if (p == 0) {
                    int o = m * 32 + og;
                    if (m < 8)       uopsw[sw(o)] = fast_tanh(Pop[o] + s);
                    else if (m < 16) ucolsw[sw(o - H)] = fast_tanh(Pcol[o - H] + s);
                    else             vhh[o - 2 * H] = s;
                }
            }
        }
        __syncthreads();
        // logits
        {
            float4 uc0 = *(const float4*)&ucolsw[pb + 0];
            float4 uc1 = *(const float4*)&ucolsw[pb + 4];
            float4 uc2 = *(const float4*)&ucolsw[pb + 8];
            float4 uc3 = *(const float4*)&ucolsw[pb + 12];
            #pragma unroll
            for (int k = 0; k < 2; ++k) {
                int o = og + k * 32;   // 0..63
                const float* row = &col_emb[o * H + p * 16];
                float4 e0 = *(const float4*)&row[0];
                float4 e1 = *(const float4*)&row[4];
                float4 e2 = *(const float4*)&row[8];
                float4 e3 = *(const float4*)&row[12];
                float s = dot4(e0, uc0) + dot4(e1, uc1) + dot4(e2, uc2) + dot4(e3, uc3);
                s = reduce16(s);
                if (p == 0) lgs[NOPS + o] = s;
            }
            if (og < NOPS) {
                float4 uo0 = *(const float4*)&uopsw[pb + 0];
                float4 uo1 = *(const float4*)&uopsw[pb + 4];
                float4 uo2 = *(const float4*)&uopsw[pb + 8];
                float4 uo3 = *(const float4*)&uopsw[pb + 12];
                const float* row = &op_emb[og * H + p * 16];
                float4 e0 = *(const float4*)&row[0];
                float4 e1 = *(const float4*)&row[4];
                float4 e2 = *(const float4*)&row[8];
                float4 e3 = *(const float4*)&row[12];
                float s = dot4(e0, uo0) + dot4(e1, uo1) + dot4(e2, uo2) + dot4(e3, uo3);
                s = reduce16(s);
                if (p == 0) lgs[og] = s;
            }
        }
        __syncthreads();
        // softmaxes
        if (tid == 0) {
            float m = -1e30f;
            for (int k = 0; k < NOPS; ++k) m = fmaxf(m, lgs[k]);
            float e[NOPS], s = 0.f;
            for (int k = 0; k < NOPS; ++k) { e[k] = expf(lgs[k] - m); s += e[k]; }
            float inv = 1.f / s;
            for (int k = 0; k < NOPS; ++k) {
                float a = e[k] * inv;
                aop_s[k] = a;
                ws[WS_AOP + t * 16 + k] = a;
            }
        }
        if (tid >= 64 && tid < 128) {
            int lane = tid - 64;
            float v = lgs[NOPS + lane];
            float m = v;
            for (int off = 1; off < 64; off <<= 1) m = fmaxf(m, __shfl_xor(m, off));
            float e = expf(v - m);
            float s = e;
            for (int off = 1; off < 64; off <<= 1) s += __shfl_xor(s, off);
            float a = __fdividef(e, s);
            acol_s[lane] = a;
            ws[WS_ACOL + t * COLSN + lane] = a;
        }
        __syncthreads();
        // h-update: h = tanh(vhh + M_op^T a_op + M_col^T a_col)
        if (tid < H) {
            float s = vhh[tid];
            const float* mop = &ws[WS_MOP + tid];
            #pragma unroll
            for (int k = 0; k < NOPS; ++k) s += aop_s[k] * mop[k * H];
            const float* mcol = &ws[WS_MCOL + tid];
            #pragma unroll 8
            for (int c = 0; c < COLSN; ++c) s += acol_s[c] * mcol[c * H];
            hhsw[sw(tid)] = fast_tanh(s);
        }
        __syncthreads();
    }
}

// ==== k_table: 782 blocks x 512 thr, grid-stride over 128-row tiles.
// No LDS staging; 8 plain accumulators + 1 atomicAdd each per block;
// ticket tail reads them with 8 PARALLEL threads (not a serial chain).
__global__ __launch_bounds__(512) void k_table(const float* __restrict__ table,
                                               float* __restrict__ ws,
                                               float* __restrict__ out) {
    __shared__ __attribute__((aligned(16))) float4 acT4[4][17];  // [q][jj], padded
    __shared__ float aop_l[64];
    __shared__ float rs3s[8][16];
    __shared__ float bred[8][8];
    __shared__ int lastblk;
    const int tid = threadIdx.x;
    const int wid = tid >> 6;
    const int lane = tid & 63;
    const int r16 = lane & 15;
    const int q = lane >> 4;

    if (tid < 64) {
        aop_l[tid] = ws[WS_AOP + tid];
        acT4[tid >> 4][tid & 15] = make_float4(
            ws[WS_ACOL + 0 * COLSN + tid], ws[WS_ACOL + 1 * COLSN + tid],
            ws[WS_ACOL + 2 * COLSN + tid], ws[WS_ACOL + 3 * COLSN + tid]);
    }
    __syncthreads();
    const float gp = ws[WS_PIV + 0];
    const float lp = ws[WS_PIV + 1];
    const float ac3 = acT4[q][r16].w;          // acol[3][lane]

    float dacc[4] = {0,0,0,0}, cacc[4] = {0,0,0,0};

    for (int tile = blockIdx.x; tile < NTBL_TILES; tile += NTBL_BLOCKS) {
        long wrow = (long)tile * 128 + wid * 16;
        bool active = wrow < ROWSN;            // per-wave granularity (16 | 200000)

        float cv[4] = {0,0,0,0}, gs[4] = {0,0,0,0}, ls[4] = {0,0,0,0};
        if (active) {
            const float* src = table + (wrow + r16) * COLSN + q * 16;
            float4 x0 = *(const float4*)&src[0];
            float4 x1 = *(const float4*)&src[4];
            float4 x2 = *(const float4*)&src[8];
            float4 x3 = *(const float4*)&src[12];
            float xs[16] = {x0.x,x0.y,x0.z,x0.w, x1.x,x1.y,x1.z,x1.w,
                            x2.x,x2.y,x2.z,x2.w, x3.x,x3.y,x3.z,x3.w};
            #pragma unroll
            for (int jj = 0; jj < 16; ++jj) {
                float x = xs[jj];
                float4 a4 = acT4[q][jj];
                float gt = (x > gp) ? 1.f : 0.f;
                float lt = (x < lp) ? 1.f : 0.f;
                cv[0] += x * a4.x;  cv[1] += x * a4.y;  cv[2] += x * a4.z;  cv[3] += x * a4.w;
                gs[0] += gt * a4.x; gs[1] += gt * a4.y; gs[2] += gt * a4.z; gs[3] += gt * a4.w;
                ls[0] += lt * a4.x; ls[1] += lt * a4.y; ls[2] += lt * a4.z; ls[3] += lt * a4.w;
            }
        }
        #pragma unroll
        for (int k = 0; k < 4; ++k) {
            cv[k] += __shfl_xor(cv[k], 16); cv[k] += __shfl_xor(cv[k], 32);
            gs[k] += __shfl_xor(gs[k], 16); gs[k] += __shfl_xor(gs[k], 32);
            ls[k] += __shfl_xor(ls[k], 16); ls[k] += __shfl_xor(ls[k], 32);
        }

        float prev1 = 1.f, prev2 = 1.f;
        #pragma unroll
        for (int t = 0; t < 4; ++t) {
            if (active) { dacc[t] += prev1 * cv[t]; cacc[t] += prev1; }
            float cg = aop_l[t*16+3], cl = aop_l[t*16+4], cmn = aop_l[t*16+5];
            float cmx = aop_l[t*16+6], co = aop_l[t*16+8];
            float cid = aop_l[t*16+0] + aop_l[t*16+1] + aop_l[t*16+2] + aop_l[t*16+7];
            float rsn = cg * gs[t] + cl * ls[t] + cmn * fminf(prev1, prev2)
                      + cmx * fmaxf(prev1, prev2) + co + cid * prev1;
            prev2 = prev1; prev1 = rsn;
        }
        if (q == 0 && active) rs3s[wid][r16] = prev1 * aop_l[3*16+7];
        // same-wave LDS write->read: in-order, no barrier needed

        if (active) {
            float* dst = out + 1 + wrow * COLSN;
            #pragma unroll 4
            for (int s = 0; s < 16; ++s)
                dst[(long)s * COLSN + lane] = rs3s[wid][s] * ac3;
        }
    }

    // block-reduce the 8 running sums; ONE atomic per accumulator per block
    float vals[8];
    #pragma unroll
    for (int t = 0; t < 4; ++t) { vals[t] = dacc[t]; vals[4 + t] = cacc[t]; }
    #pragma unroll
    for (int k = 0; k < 8; ++k) vals[k] = reduce16(vals[k]);
    if (lane == 0) {
        #pragma unroll
        for (int k = 0; k < 8; ++k) bred[wid][k] = vals[k];
    }
    __syncthreads();
    if (tid < 8) {
        float s = 0.f;
        #pragma unroll
        for (int w = 0; w < 8; ++w) s += bred[w][tid];
        atomicAdd(&ws[WS_PACC8 + tid], s);
    }
    __syncthreads();   // drains the atomics before the ticket

    if (tid == 0) {
        float old = atomicAdd(&ws[WS_TICKET], 1.0f);
        lastblk = ((int)(old + 0.5f) == NTBL_BLOCKS - 1) ? 1 : 0;
    }
    __syncthreads();
    if (lastblk) {
        if (tid < 8) bred[0][tid] = atomicAdd(&ws[WS_PACC8 + tid], 0.f);  // parallel
        __syncthreads();
        if (tid == 0) {
            float d0 = bred[0][0], d1 = bred[0][1], d2 = bred[0][2], d3 = bred[0][3];
            float c0 = bred[0][4], c1 = bred[0][5], c2 = bred[0][6], c3 = bred[0][7];
            float s0 = aop_l[0]*d0  + aop_l[1]*c0;
            float s1 = aop_l[16]*d1 + aop_l[17]*c1 + aop_l[18]*(0.f - s0);
            float s2 = aop_l[32]*d2 + aop_l[33]*c2 + aop_l[34]*(0.f - s1);
            float s3 = aop_l[48]*d3 + aop_l[49]*c3 + aop_l[50]*(s0 - s2);
            out[0] = s3;
        }
    }
}

extern "C" void kernel_launch(void* const* d_in, const int* in_sizes, int n_in,
                              void* d_out, int out_size, void* d_ws, size_t ws_size,
                              hipStream_t stream) {
    const int*   iq      = (const int*)  d_in[0];
    const float* qn      = (const float*)d_in[1];
    const int*   lwi     = (const int*)  d_in[2];
    const float* table   = (const float*)d_in[3];
    const float* E       = (const float*)d_in[4];
    const float* Wx      = (const float*)d_in[5];
    const float* Wh      = (const float*)d_in[6];
    const float* b       = (const float*)d_in[7];
    const float* W_op    = (const float*)d_in[8];
    const float* op_emb  = (const float*)d_in[9];
    const float* W_col   = (const float*)d_in[10];
    const float* col_emb = (const float*)d_in[11];
    const float* U       = (const float*)d_in[12];
    const float* W_hc    = (const float*)d_in[13];
    const float* W_hh    = (const float*)d_in[14];
    float* out = (float*)d_out;
    float* ws  = (float*)d_ws;

    hipLaunchKernelGGL(k_pre,  dim3(QLEN + 8), dim3(256), 0, stream,
                       iq, E, Wx, b, W_hc, op_emb, col_emb, ws);
    hipLaunchKernelGGL(k_rnn,  dim3(1), dim3(1024), 0, stream, Wh, lwi, U, qn, ws);
    hipLaunchKernelGGL(k_sel,  dim3(1), dim3(512), 0, stream,
                       W_op, W_col, W_hh, op_emb, col_emb, ws);
    hipLaunchKernelGGL(k_table, dim3(NTBL_BLOCKS), dim3(512), 0, stream,
                       table, ws, out);
}

// Round 9
// 196.508 us; speedup vs baseline: 1.7629x; 1.7629x over previous
//
#include <hip/hip_runtime.h>
#include <math.h>

#define H 256
#define COLSN 64
#define ROWSN 200000
#define T_STEPS 4
#define QLEN 40
#define NNUM 5
#define NOPS 9

// workspace float offsets
// UBUF/HBUF reuse the XWB region (consumed by k_rnn, which zeroes them at exit)
#define WS_UBUF   0          // 4*768 : per-step u_op|u_col|vhh
#define WS_HBUF   3072       // 4*256 : per-step h (t=1..3 used)
#define WS_XWB    0          // 40*256 (k_pre -> k_rnn only)
#define WS_Q      10240      // 256
#define WS_AOP    10496      // 4*16
#define WS_ACOL   10560      // 4*64
#define WS_PIV    10816      // [0]=g_pivot [1]=l_pivot
#define WS_TICKET 10818
#define WS_PACC8  10824      // 8 accumulators: dot[4], cnt[4]
#define WS_EPOCH  10840
#define WS_ARR    10844      // [4]
#define WS_MOP    11104      // 9*256
#define WS_MCOL   13408      // 64*256

#define NTBL_TILES  1563
#define NTBL_BLOCKS 782
#define NSEL_BLOCKS 13       // 1 master + 12 workers (64 rows each)

template<int CTRL>
__device__ __forceinline__ float dpp_add(float x) {
    int xi = __float_as_int(x);
    int yi = __builtin_amdgcn_update_dpp(0, xi, CTRL, 0xF, 0xF, true);
    return x + __int_as_float(yi);
}
#define DPP_XOR1 0xB1
#define DPP_XOR2 0x4E
#define DPP_HMIR 0x141
#define DPP_MIR  0x140

__device__ __forceinline__ float reduce16(float v) {
    v = dpp_add<DPP_XOR1>(v);
    v = dpp_add<DPP_XOR2>(v);
    v = dpp_add<DPP_HMIR>(v);
    v = dpp_add<DPP_MIR>(v);
    return v;
}

__device__ __forceinline__ float fast_tanh(float x) {
    float cx = fminf(15.f, fmaxf(-15.f, x));
    float e = __expf(2.f * cx);
    return __fdividef(e - 1.f, e + 1.f);
}

__device__ __forceinline__ float dot4(float4 a, float4 b) {
    return a.x * b.x + a.y * b.y + a.z * b.z + a.w * b.w;
}

__device__ __forceinline__ float aread(float* p) { return atomicAdd(p, 0.f); }

// LDS swizzle: +4 floats pad per 16
__device__ __forceinline__ int sw(int i) { return i + ((i >> 4) << 2); }

// ==== k_pre: blocks 0..39 -> X@Wx+b ; blocks 40..47 -> M matrices ====
__global__ __launch_bounds__(256) void k_pre(const int* __restrict__ iq,
        const float* __restrict__ E, const float* __restrict__ Wx,
        const float* __restrict__ b, const float* __restrict__ W_hc,
        const float* __restrict__ op_emb, const float* __restrict__ col_emb,
        float* __restrict__ ws) {
    int blk = blockIdx.x;
    int tid = threadIdx.x;
    if (blk < QLEN) {
        if (blk == 0 && tid < 32) ws[WS_TICKET + tid] = 0.f;  // ticket,PACC8,EPOCH,ARR
        int word = iq[blk];
        const float* erow = E + (long)word * H;
        float acc = b[tid];
        #pragma unroll 8
        for (int j = 0; j < H; ++j) acc += erow[j] * Wx[j * H + tid];
        ws[WS_XWB + blk * H + tid] = acc;
    } else {
        __shared__ __attribute__((aligned(16))) float tile[32][516];
        int bi = blk - QLEN;
        int ibase = bi * 32;
        const float4* src = (const float4*)(W_hc + (long)ibase * 2 * H);
        for (int idx = tid; idx < 32 * 128; idx += 256) {
            int row = idx >> 7, c4 = idx & 127;
            *(float4*)&tile[row][c4 * 4] = src[idx];
        }
        __syncthreads();
        int l8 = tid & 7;
        int io = tid >> 3;
        for (int k = 0; k < NOPS + COLSN; ++k) {
            const float* emb = (k < NOPS) ? (op_emb + k * H) : (col_emb + (k - NOPS) * H);
            int coff = (k < NOPS) ? 0 : H;
            float s = 0.f;
            const float* ep = emb + l8 * 32;
            const float* tr = &tile[io][coff + l8 * 32];
            #pragma unroll
            for (int ss = 0; ss < 8; ++ss) {
                int q4 = (ss + io) & 7;
                float4 e4 = *(const float4*)&ep[q4 * 4];
                float4 t4 = *(const float4*)&tr[q4 * 4];
                s += dot4(e4, t4);
            }
            s += __shfl_xor(s, 1);
            s += __shfl_xor(s, 2);
            s += __shfl_xor(s, 4);
            if (l8 == 0) {
                int dst = (k < NOPS) ? (WS_MOP + k * H) : (WS_MCOL + (k - NOPS) * H);
                ws[dst + ibase + io] = s;
            }
        }
    }
}

// ==== k_rnn: round-2 replica (~42 us). Zeros UBUF/HBUF at exit. ====
__global__ __launch_bounds__(1024) void k_rnn(const float* __restrict__ Wh,
                      const int* __restrict__ lwi,
                      const float* __restrict__ U, const float* __restrict__ qn,
                      float* __restrict__ ws) {
    __shared__ __attribute__((aligned(16))) float hbuf[2][288];
    __shared__ __attribute__((aligned(16))) float xwb[QLEN][H];
    __shared__ float Z[NNUM][H];
    __shared__ float lg[10];
    int tid = threadIdx.x;
    int g = tid >> 3;
    int p = tid & 7;

    float2 w2[32];
    #pragma unroll
    for (int jj = 0; jj < 32; ++jj)
        w2[jj] = *(const float2*)&Wh[(p * 32 + jj) * H + g * 2];

    {
        const float4* src = (const float4*)&ws[WS_XWB];
        float4* dst = (float4*)&xwb[0][0];
        for (int idx = tid; idx < QLEN * H / 4; idx += 1024) dst[idx] = src[idx];
    }
    if (tid < H) hbuf[0][tid + ((tid >> 5) << 2)] = 0.f;
    __syncthreads();

    int lw0 = lwi[0], lw1 = lwi[1], lw2 = lwi[2], lw3 = lwi[3], lw4 = lwi[4];
    int cur = 0;
    for (int t = 0; t < QLEN; ++t) {
        const float4* hv = (const float4*)&hbuf[cur][p * 36];
        float a0 = 0.f, a1 = 0.f;
        #pragma unroll
        for (int q4 = 0; q4 < 8; ++q4) {
            float4 h4 = hv[q4];
            float2 wa = w2[q4 * 4 + 0];
            float2 wb = w2[q4 * 4 + 1];
            float2 wc = w2[q4 * 4 + 2];
            float2 wd = w2[q4 * 4 + 3];
            a0 += h4.x * wa.x; a1 += h4.x * wa.y;
            a0 += h4.y * wb.x; a1 += h4.y * wb.y;
            a0 += h4.z * wc.x; a1 += h4.z * wc.y;
            a0 += h4.w * wd.x; a1 += h4.w * wd.y;
        }
        a0 = dpp_add<DPP_XOR1>(a0); a0 = dpp_add<DPP_XOR2>(a0); a0 = dpp_add<DPP_HMIR>(a0);
        a1 = dpp_add<DPP_XOR1>(a1); a1 = dpp_add<DPP_XOR2>(a1); a1 = dpp_add<DPP_HMIR>(a1);
        if (p < 2) {
            float s = (p == 0) ? a0 : a1;
            int i = g * 2 + p;
            float hn = fast_tanh(xwb[t][i] + s);
            hbuf[cur ^ 1][i + ((i >> 5) << 2)] = hn;
            if (t == lw0) Z[0][i] = hn;
            if (t == lw1) Z[1][i] = hn;
            if (t == lw2) Z[2][i] = hn;
            if (t == lw3) Z[3][i] = hn;
            if (t == lw4) Z[4][i] = hn;
        }
        __syncthreads();
        cur ^= 1;
    }
    if (tid < H) ws[WS_Q + tid] = hbuf[cur][tid + ((tid >> 5) << 2)];

    int grp = tid >> 5;
    int lane = tid & 31;
    if (grp < 10) {
        int u = grp / 5, n = grp % 5;
        float s = 0.f;
        #pragma unroll
        for (int k = 0; k < 8; ++k) {
            int j = lane + k * 32;
            s += Z[n][j] * U[u * H + j];
        }
        s += __shfl_xor(s, 1);
        s += __shfl_xor(s, 2);
        s += __shfl_xor(s, 4);
        s += __shfl_xor(s, 8);
        s += __shfl_xor(s, 16);
        if (lane == 0) lg[grp] = s;
    }
    __syncthreads();
    if (tid < 2) {
        float m = -1e30f;
        for (int n = 0; n < 5; ++n) m = fmaxf(m, lg[tid * 5 + n]);
        float e[5], s = 0.f;
        for (int n = 0; n < 5; ++n) { e[n] = expf(lg[tid * 5 + n] - m); s += e[n]; }
        float piv = 0.f;
        for (int n = 0; n < 5; ++n) piv += (e[n] / s) * qn[n];
        ws[WS_PIV + (tid == 0 ? 1 : 0)] = piv;   // PIV[0]=g, PIV[1]=l
    }
    // zero UBUF+HBUF (4096 floats) for k_sel's atomic accumulation
    for (int i = tid; i < 4096; i += 1024) ws[WS_UBUF + i] = 0.f;
}

// ==== k_sel: 13 persistent blocks, producer-consumer via device atomics ====
// Workers (blk 1..12): 64 rows each of {W_op2|W_col2|W_hh} staged in LDS once;
// per step: wait epoch -> read h -> 64 dot-256 -> atomic u write -> arrive.
// Master (blk 0): M_op/M_col in LDS; per step: wait 12 arrivals -> read u ->
// logits/softmax/h-update -> publish h + epoch.
__global__ __launch_bounds__(256) void k_sel(
        const float* __restrict__ W_op, const float* __restrict__ W_col,
        const float* __restrict__ W_hh, const float* __restrict__ op_emb,
        const float* __restrict__ col_emb, float* __restrict__ ws) {
    const int tid = threadIdx.x;
    const int blk = blockIdx.x;

    if (blk == 0) {
        // ---------------- master ----------------
        __shared__ float mopL[NOPS][H];      // 9 KB
        __shared__ float mcolL[COLSN][H];    // 64 KB
        __shared__ __attribute__((aligned(16))) float uopsw[320];
        __shared__ __attribute__((aligned(16))) float ucolsw[320];
        __shared__ float vhhL[H];
        __shared__ float lgs[80];
        __shared__ float aop_s[16], acol_s[64];

        for (int idx = tid; idx < (NOPS + COLSN) * H; idx += 256) {
            int row = idx >> 8, col = idx & 255;
            if (row < NOPS) mopL[row][col] = ws[WS_MOP + row * H + col];
            else            mcolL[row - NOPS][col] = ws[WS_MCOL + (row - NOPS) * H + col];
        }
        __syncthreads();

        for (int t = 0; t < T_STEPS; ++t) {
            if (tid == 0) {
                while (aread(&ws[WS_ARR + t]) < 11.5f) __builtin_amdgcn_s_sleep(16);
            }
            __syncthreads();
            // read u slices (device-coherent atomic reads)
            float uo = aread(&ws[WS_UBUF + t * 768 + tid]);
            float uc = aread(&ws[WS_UBUF + t * 768 + 256 + tid]);
            float vh = aread(&ws[WS_UBUF + t * 768 + 512 + tid]);
            uopsw[sw(tid)] = uo;
            ucolsw[sw(tid)] = uc;
            vhhL[tid] = vh;
            __syncthreads();
            // logits: 16 groups of 16 lanes
            {
                int g = tid >> 4, p = tid & 15;
                int pb = p * 20;
                float4 uc0 = *(const float4*)&ucolsw[pb + 0];
                float4 uc1 = *(const float4*)&ucolsw[pb + 4];
                float4 uc2 = *(const float4*)&ucolsw[pb + 8];
                float4 uc3 = *(const float4*)&ucolsw[pb + 12];
                #pragma unroll
                for (int k = 0; k < 4; ++k) {
                    int o = g + k * 16;     // 0..63
                    const float* row = &col_emb[o * H + p * 16];
                    float4 e0 = *(const float4*)&row[0];
                    float4 e1 = *(const float4*)&row[4];
                    float4 e2 = *(const float4*)&row[8];
                    float4 e3 = *(const float4*)&row[12];
                    float s = dot4(e0, uc0) + dot4(e1, uc1) + dot4(e2, uc2) + dot4(e3, uc3);
                    s = reduce16(s);
                    if (p == 0) lgs[NOPS + o] = s;
                }
                if (g < NOPS) {
                    float4 uo0 = *(const float4*)&uopsw[pb + 0];
                    float4 uo1 = *(const float4*)&uopsw[pb + 4];
                    float4 uo2 = *(const float4*)&uopsw[pb + 8];
                    float4 uo3 = *(const float4*)&uopsw[pb + 12];
                    const float* row = &op_emb[g * H + p * 16];
                    float4 e0 = *(const float4*)&row[0];
                    float4 e1 = *(const float4*)&row[4];
                    float4 e2 = *(const float4*)&row[8];
                    float4 e3 = *(const float4*)&row[12];
                    float s = dot4(e0, uo0) + dot4(e1, uo1) + dot4(e2, uo2) + dot4(e3, uo3);
                    s = reduce16(s);
                    if (p == 0) lgs[g] = s;
                }
            }
            __syncthreads();
            // softmaxes
            if (tid == 0) {
                float m = -1e30f;
                for (int k = 0; k < NOPS; ++k) m = fmaxf(m, lgs[k]);
                float e[NOPS], s = 0.f;
                for (int k = 0; k < NOPS; ++k) { e[k] = expf(lgs[k] - m); s += e[k]; }
                float inv = 1.f / s;
                for (int k = 0; k < NOPS; ++k) {
                    float a = e[k] * inv;
                    aop_s[k] = a;
                    ws[WS_AOP + t * 16 + k] = a;
                }
            }
            if (tid >= 64 && tid < 128) {
                int lane = tid - 64;
                float v = lgs[NOPS + lane];
                float m = v;
                for (int off = 1; off < 64; off <<= 1) m = fmaxf(m, __shfl_xor(m, off));
                float e = expf(v - m);
                float s = e;
                for (int off = 1; off < 64; off <<= 1) s += __shfl_xor(s, off);
                float a = __fdividef(e, s);
                acol_s[lane] = a;
                ws[WS_ACOL + t * COLSN + lane] = a;
            }
            __syncthreads();
            // h-update + publish
            if (t < T_STEPS - 1) {
                float s = vhhL[tid];
                #pragma unroll
                for (int k = 0; k < NOPS; ++k) s += aop_s[k] * mopL[k][tid];
                #pragma unroll 8
                for (int c = 0; c < COLSN; ++c) s += acol_s[c] * mcolL[c][tid];
                float hn = fast_tanh(s);
                atomicAdd(&ws[WS_HBUF + (t + 1) * 256 + tid], hn);
                __threadfence();
                __syncthreads();
                if (tid == 0) atomicAdd(&ws[WS_EPOCH], 1.f);
            }
        }
    } else {
        // ---------------- worker ----------------
        __shared__ float wlds[64 * 257];   // 65.8 KB, stride 257 (2-way banks)
        __shared__ float hl[H];
        __shared__ float Pl[64];
        __shared__ float pp[4][64];
        const int wb = (blk - 1) * 64;     // global row base (0..767)

        // stage weight slice into LDS (rows: W_op2 / W_col2 / W_hh)
        for (int idx = tid; idx < 64 * 64; idx += 256) {
            int r = idx >> 6, j4 = idx & 63;
            int o = wb + r;
            const float* src = (o < 256) ? &W_op[(long)o * 2 * H + H]
                             : (o < 512) ? &W_col[(long)(o - 256) * 2 * H + H]
                             : &W_hh[(long)(o - 512) * H];
            float4 v = *(const float4*)&src[j4 * 4];
            float* d = &wlds[r * 257 + j4 * 4];
            d[0] = v.x; d[1] = v.y; d[2] = v.z; d[3] = v.w;
        }
        // q -> LDS; P = W[:, :256] @ q for rows < 512
        hl[tid] = ws[WS_Q + tid];
        __syncthreads();
        {
            int r = tid >> 2, c = tid & 3;
            int o = wb + r;
            if (o < 512) {
                const float* src = (o < 256) ? &W_op[(long)o * 2 * H]
                                             : &W_col[(long)(o - 256) * 2 * H];
                const float* qq = &hl[c * 64];
                float s = 0.f;
                #pragma unroll
                for (int k = 0; k < 16; ++k) {
                    float4 w = *(const float4*)&src[c * 64 + k * 4];
                    s += w.x * qq[k*4] + w.y * qq[k*4+1] + w.z * qq[k*4+2] + w.w * qq[k*4+3];
                }
                s += __shfl_xor(s, 1);
                s += __shfl_xor(s, 2);
                if (c == 0) Pl[r] = s;
            } else if (c == 0) Pl[r] = 0.f;
        }
        __syncthreads();

        const int lane = tid & 63;   // row within slice
        const int seg = tid >> 6;    // 0..3 (64-col segment)
        for (int t = 0; t < T_STEPS; ++t) {
            if (t > 0) {
                if (tid == 0) {
                    while (aread(&ws[WS_EPOCH]) < (float)t - 0.5f) __builtin_amdgcn_s_sleep(16);
                }
                __syncthreads();
                hl[tid] = aread(&ws[WS_HBUF + t * 256 + tid]);
                __syncthreads();
            }
            float s = 0.f;
            if (t > 0) {
                const float* wr = &wlds[lane * 257 + seg * 64];
                const float* hh = &hl[seg * 64];
                #pragma unroll 8
                for (int j = 0; j < 64; ++j) s += wr[j] * hh[j];
            }
            pp[seg][lane] = s;
            __syncthreads();
            if (tid < 64) {
                float sum = pp[0][tid] + pp[1][tid] + pp[2][tid] + pp[3][tid];
                int o = wb + tid;
                float val = (o < 512) ? fast_tanh(Pl[tid] + sum) : sum;
                atomicAdd(&ws[WS_UBUF + t * 768 + o], val);
            }
            __threadfence();
            __syncthreads();
            if (tid == 0) atomicAdd(&ws[WS_ARR + t], 1.f);
            __syncthreads();
        }
    }
}

// ==== k_table: 782 blocks x 512 thr, grid-stride; plain accumulators,
// one atomic per accumulator per block; parallel ticketed tail. ====
__global__ __launch_bounds__(512) void k_table(const float* __restrict__ table,
                                               float* __restrict__ ws,
                                               float* __restrict__ out) {
    __shared__ __attribute__((aligned(16))) float4 acT4[4][17];
    __shared__ float aop_l[64];
    __shared__ float rs3s[8][16];
    __shared__ float bred[8][8];
    __shared__ int lastblk;
    const int tid = threadIdx.x;
    const int wid = tid >> 6;
    const int lane = tid & 63;
    const int r16 = lane & 15;
    const int q = lane >> 4;

    if (tid < 64) {
        aop_l[tid] = ws[WS_AOP + tid];
        acT4[tid >> 4][tid & 15] = make_float4(
            ws[WS_ACOL + 0 * COLSN + tid], ws[WS_ACOL + 1 * COLSN + tid],
            ws[WS_ACOL + 2 * COLSN + tid], ws[WS_ACOL + 3 * COLSN + tid]);
    }
    __syncthreads();
    const float gp = ws[WS_PIV + 0];
    const float lp = ws[WS_PIV + 1];
    const float ac3 = acT4[q][r16].w;

    float dacc[4] = {0,0,0,0}, cacc[4] = {0,0,0,0};

    for (int tile = blockIdx.x; tile < NTBL_TILES; tile += NTBL_BLOCKS) {
        long wrow = (long)tile * 128 + wid * 16;
        bool active = wrow < ROWSN;

        float cv[4] = {0,0,0,0}, gs[4] = {0,0,0,0}, ls[4] = {0,0,0,0};
        if (active) {
            const float* src = table + (wrow + r16) * COLSN + q * 16;
            float4 x0 = *(const float4*)&src[0];
            float4 x1 = *(const float4*)&src[4];
            float4 x2 = *(const float4*)&src[8];
            float4 x3 = *(const float4*)&src[12];
            float xs[16] = {x0.x,x0.y,x0.z,x0.w, x1.x,x1.y,x1.z,x1.w,
                            x2.x,x2.y,x2.z,x2.w, x3.x,x3.y,x3.z,x3.w};
            #pragma unroll
            for (int jj = 0; jj < 16; ++jj) {
                float x = xs[jj];
                float4 a4 = acT4[q][jj];
                float gt = (x > gp) ? 1.f : 0.f;
                float lt = (x < lp) ? 1.f : 0.f;
                cv[0] += x * a4.x;  cv[1] += x * a4.y;  cv[2] += x * a4.z;  cv[3] += x * a4.w;
                gs[0] += gt * a4.x; gs[1] += gt * a4.y; gs[2] += gt * a4.z; gs[3] += gt * a4.w;
                ls[0] += lt * a4.x; ls[1] += lt * a4.y; ls[2] += lt * a4.z; ls[3] += lt * a4.w;
            }
        }
        #pragma unroll
        for (int k = 0; k < 4; ++k) {
            cv[k] += __shfl_xor(cv[k], 16); cv[k] += __shfl_xor(cv[k], 32);
            gs[k] += __shfl_xor(gs[k], 16); gs[k] += __shfl_xor(gs[k], 32);
            ls[k] += __shfl_xor(ls[k], 16); ls[k] += __shfl_xor(ls[k], 32);
        }

        float prev1 = 1.f, prev2 = 1.f;
        #pragma unroll
        for (int t = 0; t < 4; ++t) {
            if (active) { dacc[t] += prev1 * cv[t]; cacc[t] += prev1; }
            float cg = aop_l[t*16+3], cl = aop_l[t*16+4], cmn = aop_l[t*16+5];
            float cmx = aop_l[t*16+6], co = aop_l[t*16+8];
            float cid = aop_l[t*16+0] + aop_l[t*16+1] + aop_l[t*16+2] + aop_l[t*16+7];
            float rsn = cg * gs[t] + cl * ls[t] + cmn * fminf(prev1, prev2)
                      + cmx * fmaxf(prev1, prev2) + co + cid * prev1;
            prev2 = prev1; prev1 = rsn;
        }
        if (q == 0 && active) rs3s[wid][r16] = prev1 * aop_l[3*16+7];

        if (active) {
            float* dst = out + 1 + wrow * COLSN;
            #pragma unroll 4
            for (int s = 0; s < 16; ++s)
                dst[(long)s * COLSN + lane] = rs3s[wid][s] * ac3;
        }
    }

    float vals[8];
    #pragma unroll
    for (int t = 0; t < 4; ++t) { vals[t] = dacc[t]; vals[4 + t] = cacc[t]; }
    #pragma unroll
    for (int k = 0; k < 8; ++k) vals[k] = reduce16(vals[k]);
    if (lane == 0) {
        #pragma unroll
        for (int k = 0; k < 8; ++k) bred[wid][k] = vals[k];
    }
    __syncthreads();
    if (tid < 8) {
        float s = 0.f;
        #pragma unroll
        for (int w = 0; w < 8; ++w) s += bred[w][tid];
        atomicAdd(&ws[WS_PACC8 + tid], s);
    }
    __syncthreads();

    if (tid == 0) {
        float old = atomicAdd(&ws[WS_TICKET], 1.0f);
        lastblk = ((int)(old + 0.5f) == NTBL_BLOCKS - 1) ? 1 : 0;
    }
    __syncthreads();
    if (lastblk) {
        if (tid < 8) bred[0][tid] = atomicAdd(&ws[WS_PACC8 + tid], 0.f);
        __syncthreads();
        if (tid == 0) {
            float d0 = bred[0][0], d1 = bred[0][1], d2 = bred[0][2], d3 = bred[0][3];
            float c0 = bred[0][4], c1 = bred[0][5], c2 = bred[0][6], c3 = bred[0][7];
            float s0 = aop_l[0]*d0  + aop_l[1]*c0;
            float s1 = aop_l[16]*d1 + aop_l[17]*c1 + aop_l[18]*(0.f - s0);
            float s2 = aop_l[32]*d2 + aop_l[33]*c2 + aop_l[34]*(0.f - s1);
            float s3 = aop_l[48]*d3 + aop_l[49]*c3 + aop_l[50]*(s0 - s2);
            out[0] = s3;
        }
    }
}

extern "C" void kernel_launch(void* const* d_in, const int* in_sizes, int n_in,
                              void* d_out, int out_size, void* d_ws, size_t ws_size,
                              hipStream_t stream) {
    const int*   iq      = (const int*)  d_in[0];
    const float* qn      = (const float*)d_in[1];
    const int*   lwi     = (const int*)  d_in[2];
    const float* table   = (const float*)d_in[3];
    const float* E       = (const float*)d_in[4];
    const float* Wx      = (const float*)d_in[5];
    const float* Wh      = (const float*)d_in[6];
    const float* b       = (const float*)d_in[7];
    const float* W_op    = (const float*)d_in[8];
    const float* op_emb  = (const float*)d_in[9];
    const float* W_col   = (const float*)d_in[10];
    const float* col_emb = (const float*)d_in[11];
    const float* U       = (const float*)d_in[12];
    const float* W_hc    = (const float*)d_in[13];
    const float* W_hh    = (const float*)d_in[14];
    float* out = (float*)d_out;
    float* ws  = (float*)d_ws;

    hipLaunchKernelGGL(k_pre,  dim3(QLEN + 8), dim3(256), 0, stream,
                       iq, E, Wx, b, W_hc, op_emb, col_emb, ws);
    hipLaunchKernelGGL(k_rnn,  dim3(1), dim3(1024), 0, stream, Wh, lwi, U, qn, ws);
    hipLaunchKernelGGL(k_sel,  dim3(NSEL_BLOCKS), dim3(256), 0, stream,
                       W_op, W_col, W_hh, op_emb, col_emb, ws);
    hipLaunchKernelGGL(k_table, dim3(NTBL_BLOCKS), dim3(512), 0, stream,
                       table, ws, out);
}

// Round 10
// 133.348 us; speedup vs baseline: 2.5979x; 1.4737x over previous
//
#include <hip/hip_runtime.h>
#include <math.h>

#define H 256
#define COLSN 64
#define ROWSN 200000
#define T_STEPS 4
#define QLEN 40
#define NNUM 5
#define NOPS 9

// workspace float offsets
// UBUF/HBUF reuse the XWB region (consumed by k_rnn, which zeroes them at exit)
#define WS_UBUF   0          // 4*768 : per-step u_op|u_col|vhh
#define WS_HBUF   3072       // 4*256 : per-step h (t=1..3 used)
#define WS_XWB    0          // 40*256 (k_pre -> k_rnn only)
#define WS_Q      10240      // 256
#define WS_AOP    10496      // 4*16
#define WS_ACOL   10560      // 4*64
#define WS_PIV    10816      // [0]=g_pivot [1]=l_pivot
#define WS_TICKET 10818
#define WS_PACC8  10824      // 8 accumulators: dot[4], cnt[4]
#define WS_EPOCH  10840
#define WS_ARR    10844      // [4]
#define WS_MOP    11104      // 9*256
#define WS_MCOL   13408      // 64*256

#define NTBL_TILES  1563
#define NTBL_BLOCKS 782
#define NSEL_BLOCKS 13       // 1 master + 12 workers (64 rows each)
#define NM_BLOCKS   72       // 8 itiles x 9 kgroups

template<int CTRL>
__device__ __forceinline__ float dpp_add(float x) {
    int xi = __float_as_int(x);
    int yi = __builtin_amdgcn_update_dpp(0, xi, CTRL, 0xF, 0xF, true);
    return x + __int_as_float(yi);
}
#define DPP_XOR1 0xB1
#define DPP_XOR2 0x4E
#define DPP_HMIR 0x141
#define DPP_MIR  0x140

__device__ __forceinline__ float reduce16(float v) {
    v = dpp_add<DPP_XOR1>(v);
    v = dpp_add<DPP_XOR2>(v);
    v = dpp_add<DPP_HMIR>(v);
    v = dpp_add<DPP_MIR>(v);
    return v;
}

__device__ __forceinline__ float fast_tanh(float x) {
    float cx = fminf(15.f, fmaxf(-15.f, x));
    float e = __expf(2.f * cx);
    return __fdividef(e - 1.f, e + 1.f);
}

__device__ __forceinline__ float dot4(float4 a, float4 b) {
    return a.x * b.x + a.y * b.y + a.z * b.z + a.w * b.w;
}

__device__ __forceinline__ float aread(float* p) { return atomicAdd(p, 0.f); }

// LDS swizzle: +4 floats pad per 16
__device__ __forceinline__ int sw(int i) { return i + ((i >> 4) << 2); }

// ==== k_pre: blocks 0..39 -> X@Wx+b (4-acc ILP);
// ==== blocks 40..111 -> M matrices (8 itiles x 9 kgroups, <=9 iters each) ====
__global__ __launch_bounds__(256) void k_pre(const int* __restrict__ iq,
        const float* __restrict__ E, const float* __restrict__ Wx,
        const float* __restrict__ b, const float* __restrict__ W_hc,
        const float* __restrict__ op_emb, const float* __restrict__ col_emb,
        float* __restrict__ ws) {
    int blk = blockIdx.x;
    int tid = threadIdx.x;
    if (blk < QLEN) {
        if (blk == 0 && tid < 32) ws[WS_TICKET + tid] = 0.f;  // ticket,PACC8,EPOCH,ARR
        int word = iq[blk];
        const float* erow = E + (long)word * H;
        float a0 = b[tid], a1 = 0.f, a2 = 0.f, a3 = 0.f;
        #pragma unroll 8
        for (int j = 0; j < H; j += 4) {
            a0 += erow[j + 0] * Wx[(j + 0) * H + tid];
            a1 += erow[j + 1] * Wx[(j + 1) * H + tid];
            a2 += erow[j + 2] * Wx[(j + 2) * H + tid];
            a3 += erow[j + 3] * Wx[(j + 3) * H + tid];
        }
        ws[WS_XWB + blk * H + tid] = (a0 + a1) + (a2 + a3);
    } else {
        // M_op[k][i] = op_emb[k].W_hc[i][0:256] ; M_col[c][i] = col_emb[c].W_hc[i][256:512]
        __shared__ __attribute__((aligned(16))) float tile[32][268];  // 34 KB
        int mb = blk - QLEN;          // 0..71
        int bi = mb / 9;              // itile 0..7
        int kg = mb % 9;              // kgroup 0..8
        int ibase = bi * 32;
        int coff = (kg == 0) ? 0 : H;
        // stage 32 rows x 256 cols (the needed half), coalesced
        for (int idx = tid; idx < 32 * 64; idx += 256) {
            int r = idx >> 6, c4 = idx & 63;
            float4 v = *(const float4*)&W_hc[(long)(ibase + r) * 2 * H + coff + c4 * 4];
            float* d = &tile[r][c4 * 4];
            d[0] = v.x; d[1] = v.y; d[2] = v.z; d[3] = v.w;
        }
        __syncthreads();
        int l8 = tid & 7;
        int io = tid >> 3;            // 0..31
        int nk = (kg == 0) ? NOPS : 8;
        for (int kk = 0; kk < nk; ++kk) {
            const float* emb;
            int dst;
            if (kg == 0) { emb = op_emb + kk * H;                 dst = WS_MOP + kk * H; }
            else { int c = (kg - 1) * 8 + kk; emb = col_emb + c * H; dst = WS_MCOL + c * H; }
            float s = 0.f;
            const float* ep = emb + l8 * 32;
            const float* tr = &tile[io][l8 * 32];
            #pragma unroll
            for (int ss = 0; ss < 8; ++ss) {
                int q4 = (ss + l8) & 7;               // rotate by l8: spreads banks
                float4 e4 = *(const float4*)&ep[q4 * 4];
                float4 t4 = *(const float4*)&tr[q4 * 4];
                s += dot4(e4, t4);
            }
            s += __shfl_xor(s, 1);
            s += __shfl_xor(s, 2);
            s += __shfl_xor(s, 4);
            if (l8 == 0) ws[dst + ibase + io] = s;
        }
    }
}

// ==== k_rnn: round-2 replica (~42 us). Zeros UBUF/HBUF at exit. ====
__global__ __launch_bounds__(1024) void k_rnn(const float* __restrict__ Wh,
                      const int* __restrict__ lwi,
                      const float* __restrict__ U, const float* __restrict__ qn,
                      float* __restrict__ ws) {
    __shared__ __attribute__((aligned(16))) float hbuf[2][288];
    __shared__ __attribute__((aligned(16))) float xwb[QLEN][H];
    __shared__ float Z[NNUM][H];
    __shared__ float lg[10];
    int tid = threadIdx.x;
    int g = tid >> 3;
    int p = tid & 7;

    float2 w2[32];
    #pragma unroll
    for (int jj = 0; jj < 32; ++jj)
        w2[jj] = *(const float2*)&Wh[(p * 32 + jj) * H + g * 2];

    {
        const float4* src = (const float4*)&ws[WS_XWB];
        float4* dst = (float4*)&xwb[0][0];
        for (int idx = tid; idx < QLEN * H / 4; idx += 1024) dst[idx] = src[idx];
    }
    if (tid < H) hbuf[0][tid + ((tid >> 5) << 2)] = 0.f;
    __syncthreads();

    int lw0 = lwi[0], lw1 = lwi[1], lw2 = lwi[2], lw3 = lwi[3], lw4 = lwi[4];
    int cur = 0;
    for (int t = 0; t < QLEN; ++t) {
        const float4* hv = (const float4*)&hbuf[cur][p * 36];
        float a0 = 0.f, a1 = 0.f;
        #pragma unroll
        for (int q4 = 0; q4 < 8; ++q4) {
            float4 h4 = hv[q4];
            float2 wa = w2[q4 * 4 + 0];
            float2 wb = w2[q4 * 4 + 1];
            float2 wc = w2[q4 * 4 + 2];
            float2 wd = w2[q4 * 4 + 3];
            a0 += h4.x * wa.x; a1 += h4.x * wa.y;
            a0 += h4.y * wb.x; a1 += h4.y * wb.y;
            a0 += h4.z * wc.x; a1 += h4.z * wc.y;
            a0 += h4.w * wd.x; a1 += h4.w * wd.y;
        }
        a0 = dpp_add<DPP_XOR1>(a0); a0 = dpp_add<DPP_XOR2>(a0); a0 = dpp_add<DPP_HMIR>(a0);
        a1 = dpp_add<DPP_XOR1>(a1); a1 = dpp_add<DPP_XOR2>(a1); a1 = dpp_add<DPP_HMIR>(a1);
        if (p < 2) {
            float s = (p == 0) ? a0 : a1;
            int i = g * 2 + p;
            float hn = fast_tanh(xwb[t][i] + s);
            hbuf[cur ^ 1][i + ((i >> 5) << 2)] = hn;
            if (t == lw0) Z[0][i] = hn;
            if (t == lw1) Z[1][i] = hn;
            if (t == lw2) Z[2][i] = hn;
            if (t == lw3) Z[3][i] = hn;
            if (t == lw4) Z[4][i] = hn;
        }
        __syncthreads();
        cur ^= 1;
    }
    if (tid < H) ws[WS_Q + tid] = hbuf[cur][tid + ((tid >> 5) << 2)];

    int grp = tid >> 5;
    int lane = tid & 31;
    if (grp < 10) {
        int u = grp / 5, n = grp % 5;
        float s = 0.f;
        #pragma unroll
        for (int k = 0; k < 8; ++k) {
            int j = lane + k * 32;
            s += Z[n][j] * U[u * H + j];
        }
        s += __shfl_xor(s, 1);
        s += __shfl_xor(s, 2);
        s += __shfl_xor(s, 4);
        s += __shfl_xor(s, 8);
        s += __shfl_xor(s, 16);
        if (lane == 0) lg[grp] = s;
    }
    __syncthreads();
    if (tid < 2) {
        float m = -1e30f;
        for (int n = 0; n < 5; ++n) m = fmaxf(m, lg[tid * 5 + n]);
        float e[5], s = 0.f;
        for (int n = 0; n < 5; ++n) { e[n] = expf(lg[tid * 5 + n] - m); s += e[n]; }
        float piv = 0.f;
        for (int n = 0; n < 5; ++n) piv += (e[n] / s) * qn[n];
        ws[WS_PIV + (tid == 0 ? 1 : 0)] = piv;   // PIV[0]=g, PIV[1]=l
    }
    // zero UBUF+HBUF (4096 floats) for k_sel's atomic accumulation
    for (int i = tid; i < 4096; i += 1024) ws[WS_UBUF + i] = 0.f;
}

// ==== k_sel: 13 persistent blocks, producer-consumer via device atomics ====
__global__ __launch_bounds__(256) void k_sel(
        const float* __restrict__ W_op, const float* __restrict__ W_col,
        const float* __restrict__ W_hh, const float* __restrict__ op_emb,
        const float* __restrict__ col_emb, float* __restrict__ ws) {
    const int tid = threadIdx.x;
    const int blk = blockIdx.x;

    if (blk == 0) {
        // ---------------- master ----------------
        __shared__ float mopL[NOPS][H];      // 9 KB
        __shared__ float mcolL[COLSN][H];    // 64 KB
        __shared__ __attribute__((aligned(16))) float uopsw[320];
        __shared__ __attribute__((aligned(16))) float ucolsw[320];
        __shared__ float vhhL[H];
        __shared__ float lgs[80];
        __shared__ float aop_s[16], acol_s[64];

        for (int idx = tid; idx < (NOPS + COLSN) * H; idx += 256) {
            int row = idx >> 8, col = idx & 255;
            if (row < NOPS) mopL[row][col] = ws[WS_MOP + row * H + col];
            else            mcolL[row - NOPS][col] = ws[WS_MCOL + (row - NOPS) * H + col];
        }
        __syncthreads();

        for (int t = 0; t < T_STEPS; ++t) {
            if (tid == 0) {
                while (aread(&ws[WS_ARR + t]) < 11.5f) __builtin_amdgcn_s_sleep(16);
            }
            __syncthreads();
            float uo = aread(&ws[WS_UBUF + t * 768 + tid]);
            float uc = aread(&ws[WS_UBUF + t * 768 + 256 + tid]);
            float vh = aread(&ws[WS_UBUF + t * 768 + 512 + tid]);
            uopsw[sw(tid)] = uo;
            ucolsw[sw(tid)] = uc;
            vhhL[tid] = vh;
            __syncthreads();
            // logits: 16 groups of 16 lanes
            {
                int g = tid >> 4, p = tid & 15;
                int pb = p * 20;
                float4 uc0 = *(const float4*)&ucolsw[pb + 0];
                float4 uc1 = *(const float4*)&ucolsw[pb + 4];
                float4 uc2 = *(const float4*)&ucolsw[pb + 8];
                float4 uc3 = *(const float4*)&ucolsw[pb + 12];
                #pragma unroll
                for (int k = 0; k < 4; ++k) {
                    int o = g + k * 16;     // 0..63
                    const float* row = &col_emb[o * H + p * 16];
                    float4 e0 = *(const float4*)&row[0];
                    float4 e1 = *(const float4*)&row[4];
                    float4 e2 = *(const float4*)&row[8];
                    float4 e3 = *(const float4*)&row[12];
                    float s = dot4(e0, uc0) + dot4(e1, uc1) + dot4(e2, uc2) + dot4(e3, uc3);
                    s = reduce16(s);
                    if (p == 0) lgs[NOPS + o] = s;
                }
                if (g < NOPS) {
                    float4 uo0 = *(const float4*)&uopsw[pb + 0];
                    float4 uo1 = *(const float4*)&uopsw[pb + 4];
                    float4 uo2 = *(const float4*)&uopsw[pb + 8];
                    float4 uo3 = *(const float4*)&uopsw[pb + 12];
                    const float* row = &op_emb[g * H + p * 16];
                    float4 e0 = *(const float4*)&row[0];
                    float4 e1 = *(const float4*)&row[4];
                    float4 e2 = *(const float4*)&row[8];
                    float4 e3 = *(const float4*)&row[12];
                    float s = dot4(e0, uo0) + dot4(e1, uo1) + dot4(e2, uo2) + dot4(e3, uo3);
                    s = reduce16(s);
                    if (p == 0) lgs[g] = s;
                }
            }
            __syncthreads();
            // softmaxes
            if (tid == 0) {
                float m = -1e30f;
                for (int k = 0; k < NOPS; ++k) m = fmaxf(m, lgs[k]);
                float e[NOPS], s = 0.f;
                for (int k = 0; k < NOPS; ++k) { e[k] = expf(lgs[k] - m); s += e[k]; }
                float inv = 1.f / s;
                for (int k = 0; k < NOPS; ++k) {
                    float a = e[k] * inv;
                    aop_s[k] = a;
                    ws[WS_AOP + t * 16 + k] = a;
                }
            }
            if (tid >= 64 && tid < 128) {
                int lane = tid - 64;
                float v = lgs[NOPS + lane];
                float m = v;
                for (int off = 1; off < 64; off <<= 1) m = fmaxf(m, __shfl_xor(m, off));
                float e = expf(v - m);
                float s = e;
                for (int off = 1; off < 64; off <<= 1) s += __shfl_xor(s, off);
                float a = __fdividef(e, s);
                acol_s[lane] = a;
                ws[WS_ACOL + t * COLSN + lane] = a;
            }
            __syncthreads();
            // h-update + publish
            if (t < T_STEPS - 1) {
                float s = vhhL[tid];
                #pragma unroll
                for (int k = 0; k < NOPS; ++k) s += aop_s[k] * mopL[k][tid];
                #pragma unroll 8
                for (int c = 0; c < COLSN; ++c) s += acol_s[c] * mcolL[c][tid];
                float hn = fast_tanh(s);
                atomicAdd(&ws[WS_HBUF + (t + 1) * 256 + tid], hn);
                __threadfence();
                __syncthreads();
                if (tid == 0) atomicAdd(&ws[WS_EPOCH], 1.f);
            }
        }
    } else {
        // ---------------- worker ----------------
        __shared__ float wlds[64 * 257];   // 65.8 KB
        __shared__ float hl[H];
        __shared__ float Pl[64];
        __shared__ float pp[4][64];
        const int wb = (blk - 1) * 64;     // global row base (0..767)

        for (int idx = tid; idx < 64 * 64; idx += 256) {
            int r = idx >> 6, j4 = idx & 63;
            int o = wb + r;
            const float* src = (o < 256) ? &W_op[(long)o * 2 * H + H]
                             : (o < 512) ? &W_col[(long)(o - 256) * 2 * H + H]
                             : &W_hh[(long)(o - 512) * H];
            float4 v = *(const float4*)&src[j4 * 4];
            float* d = &wlds[r * 257 + j4 * 4];
            d[0] = v.x; d[1] = v.y; d[2] = v.z; d[3] = v.w;
        }
        hl[tid] = ws[WS_Q + tid];
        __syncthreads();
        {
            int r = tid >> 2, c = tid & 3;
            int o = wb + r;
            if (o < 512) {
                const float* src = (o < 256) ? &W_op[(long)o * 2 * H]
                                             : &W_col[(long)(o - 256) * 2 * H];
                const float* qq = &hl[c * 64];
                float s = 0.f;
                #pragma unroll
                for (int k = 0; k < 16; ++k) {
                    float4 w = *(const float4*)&src[c * 64 + k * 4];
                    s += w.x * qq[k*4] + w.y * qq[k*4+1] + w.z * qq[k*4+2] + w.w * qq[k*4+3];
                }
                s += __shfl_xor(s, 1);
                s += __shfl_xor(s, 2);
                if (c == 0) Pl[r] = s;
            } else if (c == 0) Pl[r] = 0.f;
        }
        __syncthreads();

        const int lane = tid & 63;
        const int seg = tid >> 6;
        for (int t = 0; t < T_STEPS; ++t) {
            if (t > 0) {
                if (tid == 0) {
                    while (aread(&ws[WS_EPOCH]) < (float)t - 0.5f) __builtin_amdgcn_s_sleep(16);
                }
                __syncthreads();
                hl[tid] = aread(&ws[WS_HBUF + t * 256 + tid]);
                __syncthreads();
            }
            float s = 0.f;
            if (t > 0) {
                const float* wr = &wlds[lane * 257 + seg * 64];
                const float* hh = &hl[seg * 64];
                #pragma unroll 8
                for (int j = 0; j < 64; ++j) s += wr[j] * hh[j];
            }
            pp[seg][lane] = s;
            __syncthreads();
            if (tid < 64) {
                float sum = pp[0][tid] + pp[1][tid] + pp[2][tid] + pp[3][tid];
                int o = wb + tid;
                float val = (o < 512) ? fast_tanh(Pl[tid] + sum) : sum;
                atomicAdd(&ws[WS_UBUF + t * 768 + o], val);
            }
            __threadfence();
            __syncthreads();
            if (tid == 0) atomicAdd(&ws[WS_ARR + t], 1.f);
            __syncthreads();
        }
    }
}

// ==== k_table: 782 blocks x 512 thr, grid-stride; plain accumulators,
// one atomic per accumulator per block; parallel ticketed tail. ====
__global__ __launch_bounds__(512) void k_table(const float* __restrict__ table,
                                               float* __restrict__ ws,
                                               float* __restrict__ out) {
    __shared__ __attribute__((aligned(16))) float4 acT4[4][17];
    __shared__ float aop_l[64];
    __shared__ float rs3s[8][16];
    __shared__ float bred[8][8];
    __shared__ int lastblk;
    const int tid = threadIdx.x;
    const int wid = tid >> 6;
    const int lane = tid & 63;
    const int r16 = lane & 15;
    const int q = lane >> 4;

    if (tid < 64) {
        aop_l[tid] = ws[WS_AOP + tid];
        acT4[tid >> 4][tid & 15] = make_float4(
            ws[WS_ACOL + 0 * COLSN + tid], ws[WS_ACOL + 1 * COLSN + tid],
            ws[WS_ACOL + 2 * COLSN + tid], ws[WS_ACOL + 3 * COLSN + tid]);
    }
    __syncthreads();
    const float gp = ws[WS_PIV + 0];
    const float lp = ws[WS_PIV + 1];
    const float ac3 = acT4[q][r16].w;

    float dacc[4] = {0,0,0,0}, cacc[4] = {0,0,0,0};

    for (int tile = blockIdx.x; tile < NTBL_TILES; tile += NTBL_BLOCKS) {
        long wrow = (long)tile * 128 + wid * 16;
        bool active = wrow < ROWSN;

        float cv[4] = {0,0,0,0}, gs[4] = {0,0,0,0}, ls[4] = {0,0,0,0};
        if (active) {
            const float* src = table + (wrow + r16) * COLSN + q * 16;
            float4 x0 = *(const float4*)&src[0];
            float4 x1 = *(const float4*)&src[4];
            float4 x2 = *(const float4*)&src[8];
            float4 x3 = *(const float4*)&src[12];
            float xs[16] = {x0.x,x0.y,x0.z,x0.w, x1.x,x1.y,x1.z,x1.w,
                            x2.x,x2.y,x2.z,x2.w, x3.x,x3.y,x3.z,x3.w};
            #pragma unroll
            for (int jj = 0; jj < 16; ++jj) {
                float x = xs[jj];
                float4 a4 = acT4[q][jj];
                float gt = (x > gp) ? 1.f : 0.f;
                float lt = (x < lp) ? 1.f : 0.f;
                cv[0] += x * a4.x;  cv[1] += x * a4.y;  cv[2] += x * a4.z;  cv[3] += x * a4.w;
                gs[0] += gt * a4.x; gs[1] += gt * a4.y; gs[2] += gt * a4.z; gs[3] += gt * a4.w;
                ls[0] += lt * a4.x; ls[1] += lt * a4.y; ls[2] += lt * a4.z; ls[3] += lt * a4.w;
            }
        }
        #pragma unroll
        for (int k = 0; k < 4; ++k) {
            cv[k] += __shfl_xor(cv[k], 16); cv[k] += __shfl_xor(cv[k], 32);
            gs[k] += __shfl_xor(gs[k], 16); gs[k] += __shfl_xor(gs[k], 32);
            ls[k] += __shfl_xor(ls[k], 16); ls[k] += __shfl_xor(ls[k], 32);
        }

        float prev1 = 1.f, prev2 = 1.f;
        #pragma unroll
        for (int t = 0; t < 4; ++t) {
            if (active) { dacc[t] += prev1 * cv[t]; cacc[t] += prev1; }
            float cg = aop_l[t*16+3], cl = aop_l[t*16+4], cmn = aop_l[t*16+5];
            float cmx = aop_l[t*16+6], co = aop_l[t*16+8];
            float cid = aop_l[t*16+0] + aop_l[t*16+1] + aop_l[t*16+2] + aop_l[t*16+7];
            float rsn = cg * gs[t] + cl * ls[t] + cmn * fminf(prev1, prev2)
                      + cmx * fmaxf(prev1, prev2) + co + cid * prev1;
            prev2 = prev1; prev1 = rsn;
        }
        if (q == 0 && active) rs3s[wid][r16] = prev1 * aop_l[3*16+7];

        if (active) {
            float* dst = out + 1 + wrow * COLSN;
            #pragma unroll 4
            for (int s = 0; s < 16; ++s)
                dst[(long)s * COLSN + lane] = rs3s[wid][s] * ac3;
        }
    }

    float vals[8];
    #pragma unroll
    for (int t = 0; t < 4; ++t) { vals[t] = dacc[t]; vals[4 + t] = cacc[t]; }
    #pragma unroll
    for (int k = 0; k < 8; ++k) vals[k] = reduce16(vals[k]);
    if (lane == 0) {
        #pragma unroll
        for (int k = 0; k < 8; ++k) bred[wid][k] = vals[k];
    }
    __syncthreads();
    if (tid < 8) {
        float s = 0.f;
        #pragma unroll
        for (int w = 0; w < 8; ++w) s += bred[w][tid];
        atomicAdd(&ws[WS_PACC8 + tid], s);
    }
    __syncthreads();

    if (tid == 0) {
        float old = atomicAdd(&ws[WS_TICKET], 1.0f);
        lastblk = ((int)(old + 0.5f) == NTBL_BLOCKS - 1) ? 1 : 0;
    }
    __syncthreads();
    if (lastblk) {
        if (tid < 8) bred[0][tid] = atomicAdd(&ws[WS_PACC8 + tid], 0.f);
        __syncthreads();
        if (tid == 0) {
            float d0 = bred[0][0], d1 = bred[0][1], d2 = bred[0][2], d3 = bred[0][3];
            float c0 = bred[0][4], c1 = bred[0][5], c2 = bred[0][6], c3 = bred[0][7];
            float s0 = aop_l[0]*d0  + aop_l[1]*c0;
            float s1 = aop_l[16]*d1 + aop_l[17]*c1 + aop_l[18]*(0.f - s0);
            float s2 = aop_l[32]*d2 + aop_l[33]*c2 + aop_l[34]*(0.f - s1);
            float s3 = aop_l[48]*d3 + aop_l[49]*c3 + aop_l[50]*(s0 - s2);
            out[0] = s3;
        }
    }
}

extern "C" void kernel_launch(void* const* d_in, const int* in_sizes, int n_in,
                              void* d_out, int out_size, void* d_ws, size_t ws_size,
                              hipStream_t stream) {
    const int*   iq      = (const int*)  d_in[0];
    const float* qn      = (const float*)d_in[1];
    const int*   lwi     = (const int*)  d_in[2];
    const float* table   = (const float*)d_in[3];
    const float* E       = (const float*)d_in[4];
    const float* Wx      = (const float*)d_in[5];
    const float* Wh      = (const float*)d_in[6];
    const float* b       = (const float*)d_in[7];
    const float* W_op    = (const float*)d_in[8];
    const float* op_emb  = (const float*)d_in[9];
    const float* W_col   = (const float*)d_in[10];
    const float* col_emb = (const float*)d_in[11];
    const float* U       = (const float*)d_in[12];
    const float* W_hc    = (const float*)d_in[13];
    const float* W_hh    = (const float*)d_in[14];
    float* out = (float*)d_out;
    float* ws  = (float*)d_ws;

    hipLaunchKernelGGL(k_pre,  dim3(QLEN + NM_BLOCKS), dim3(256), 0, stream,
                       iq, E, Wx, b, W_hc, op_emb, col_emb, ws);
    hipLaunchKernelGGL(k_rnn,  dim3(1), dim3(1024), 0, stream, Wh, lwi, U, qn, ws);
    hipLaunchKernelGGL(k_sel,  dim3(NSEL_BLOCKS), dim3(256), 0, stream,
                       W_op, W_col, W_hh, op_emb, col_emb, ws);
    hipLaunchKernelGGL(k_table, dim3(NTBL_BLOCKS), dim3(512), 0, stream,
                       table, ws, out);
}